// Round 8
// baseline (797.605 us; speedup 1.0000x reference)
//
#include <hip/hip_runtime.h>
#include <hip/hip_cooperative_groups.h>
#include <math.h>

namespace cg = cooperative_groups;

// Model dims
#define BB 8
#define TT 150
#define DD 30
#define HH 5
#define HD 6
#define LL 3
#define NI 40            // B*H heads per stream
#define ROWF (TT*BB*DD)  // 36000 floats per [T,B,D] buffer
#define RSTR 8           // padded LDS row stride in halves (16B -> ds_read_b128)
#define NR 152           // padded row count (150 data + vbar + zero)
#define SMEMN 9904       // shared float pool (39.6 KB)

typedef _Float16 half8 __attribute__((ext_vector_type(8)));
typedef float f32x16 __attribute__((ext_vector_type(16)));

struct Params {
    const float *x_l, *x_a, *x_v, *Wl, *Wa, *Wv;
    const float *in_w, *in_b, *out_w, *out_b;
    const float *l1w, *l1b, *l2w, *l2b;
    const float *n1g, *n1b, *n2g, *n2b;
    const float *p1w, *p1b, *p2w, *p2b, *oww, *obb;
    float *pl, *pa, *pv, *h, *q, *k_all, *v_all, *at, *out;
};

__device__ __forceinline__ float wsum(float v) {
    #pragma unroll
    for (int m = 32; m > 0; m >>= 1) v += __shfl_xor(v, m, 64);
    return v;
}

// ===================== MEGA (cooperative) =====================
__global__ __launch_bounds__(256, 2) void mega_kernel(Params P) {
    cg::grid_group grid = cg::this_grid();
    __shared__ __align__(16) float sm[SMEMN];
    const int tid = threadIdx.x;
    const int w = tid >> 6, lane = tid & 63;
    const int nbk = gridDim.x, bid = blockIdx.x;

    // ---- Phase 1: input projections (W staged f16) ----
    {
        _Float16* WH = (_Float16*)sm;           // 30*301 halves
        float* xr = sm + 4520;                  // [4][304]
        for (int task = bid; task < 900; task += nbk) {
            int which = task / 300;
            int rowu = (task % 300) * 4 + w;
            int t = rowu / BB, b = rowu % BB;
            const float* x = which == 0 ? P.x_l : (which == 1 ? P.x_a : P.x_v);
            const float* W = which == 0 ? P.Wl : (which == 1 ? P.Wa : P.Wv);
            float* outp = which == 0 ? P.pl : (which == 1 ? P.pa : P.pv);
            int Cin = which == 0 ? 300 : (which == 1 ? 74 : 35);
            int cst = Cin | 1;
            for (int j = tid; j < DD * Cin; j += 256)
                WH[(j / Cin) * cst + (j % Cin)] = (_Float16)W[j];
            const float* xp = x + ((size_t)b * TT + t) * Cin;
            for (int j = lane; j < Cin; j += 64) xr[w * 304 + j] = xp[j];
            __syncthreads();
            int d = lane >> 1, jh = lane & 1;
            int h1 = Cin >> 1;
            int j0 = jh ? h1 : 0, j1 = jh ? Cin : h1;
            const _Float16* wr = WH + (d < DD ? d : 0) * cst;
            float acc = 0.f;
            for (int j = j0; j < j1; j++) acc += xr[w * 304 + j] * (float)wr[j];
            acc += __shfl_xor(acc, 1, 64);
            if (jh == 0 && d < DD) outp[t * (BB * DD) + b * DD + d] = acc;
            __syncthreads();
        }
    }
    __threadfence();
    grid.sync();

    // ---- Phase 2: k/v for all 6 (s,l), q for layer 0 ----
    {
        float* iwS = sm;            // 1800
        float* xn  = sm + 1800;     // [4][2][30]
        for (int task = bid; task < 1800; task += nbk) {
            int po = task / 300;
            int s = po / LL;
            int tb = (task % 300) * 4 + w;
            int t = tb / BB, b = tb % BB;
            const float* xk = (s == 0) ? P.pa : P.pv;
            const float* xv = (s == 0) ? P.pv : P.pa;
            const float* iw = P.in_w + (size_t)po * 2700 + 900;
            const float* ib = P.in_b + (size_t)po * 90;
            const float* g  = P.n1g + (size_t)po * 30;
            const float* bb = P.n1b + (size_t)po * 30;
            for (int j = tid; j < 1800; j += 256) iwS[j] = iw[j];
            const float* rows[2] = { xk + (size_t)tb * 30, xv + (size_t)tb * 30 };
            for (int r = 0; r < 2; r++) {
                float xval = (lane < 30) ? rows[r][lane] : 0.f;
                float mean = wsum(xval) * (1.f / 30.f);
                float dv = (lane < 30) ? (xval - mean) : 0.f;
                float var = wsum(dv * dv) * (1.f / 30.f);
                float inv = rsqrtf(var + 1e-5f);
                if (lane < 30) xn[w * 60 + r * 30 + lane] = dv * inv * g[lane] + bb[lane];
            }
            __syncthreads();
            if (lane < 60) {
                int which = lane / 30, dd = lane % 30;
                const float* wr = iwS + lane * 30;
                const float* xv2 = xn + w * 60 + which * 30;
                float acc = 0.f;
                #pragma unroll 6
                for (int j = 0; j < 30; j++) acc += wr[j] * xv2[j];
                acc += ib[30 + lane];
                int i = b * HH + dd / HD, hd = dd % HD;
                float* dst = which ? P.v_all : P.k_all;
                dst[((size_t)po * NI + i) * (TT * HD) + t * HD + hd] = acc;
            }
            __syncthreads();
        }
        float* iwq = sm;            // 900
        float* xn2 = sm + 900;      // [4][30]
        for (int task = bid; task < 600; task += nbk) {
            int s = task / 300;
            int tb = (task % 300) * 4 + w;
            int t = tb / BB, b = tb % BB;
            int po = s * LL;
            const float* iw = P.in_w + (size_t)po * 2700;
            const float* ib = P.in_b + (size_t)po * 90;
            const float* g  = P.n1g + (size_t)po * 30;
            const float* bb = P.n1b + (size_t)po * 30;
            for (int j = tid; j < 900; j += 256) iwq[j] = iw[j];
            const float* row = P.pl + (size_t)tb * 30;
            float xval = (lane < 30) ? row[lane] : 0.f;
            float mean = wsum(xval) * (1.f / 30.f);
            float dv = (lane < 30) ? (xval - mean) : 0.f;
            float var = wsum(dv * dv) * (1.f / 30.f);
            float inv = rsqrtf(var + 1e-5f);
            if (lane < 30) xn2[w * 30 + lane] = dv * inv * g[lane] + bb[lane];
            __syncthreads();
            if (lane < 30) {
                const float* wr = iwq + lane * 30;
                float acc = 0.f;
                #pragma unroll 6
                for (int j = 0; j < 30; j++) acc += wr[j] * xn2[w * 30 + j];
                acc = (acc + ib[lane]) * 0.40824829046386307f;
                int i = b * HH + lane / HD, hd = lane % HD;
                P.q[((size_t)s * NI + i) * (TT * HD) + t * HD + hd] = acc;
            }
            __syncthreads();
        }
    }
    __threadfence();
    grid.sync();

    // ---- Layers ----
    for (int l = 0; l < LL; l++) {
        // score
        {
            _Float16* qsh = (_Float16*)sm;
            _Float16* ksh = qsh + NR * RSTR;
            _Float16* vsh = ksh + NR * RSTR;
            const int lo = lane & 31, hf = lane >> 5;
            for (int task = bid; task < 1520; task += nbk) {
                int s = task / 760;
                int rem = task % 760;
                int i = rem / 19;
                int g = rem % 19;
                int po = s * LL + l;
                int* z = (int*)sm;
                for (int idx = tid; idx < 3 * NR * RSTR / 2; idx += 256) z[idx] = 0;
                __syncthreads();
                const float* qg = P.q + (size_t)(s * NI + i) * (TT * HD);
                const float* kg = P.k_all + (size_t)(po * NI + i) * (TT * HD);
                const float* vg = P.v_all + (size_t)(po * NI + i) * (TT * HD);
                for (int idx = tid; idx < TT * HD; idx += 256) {
                    int dst = (idx / HD) * RSTR + (idx % HD);
                    qsh[dst] = (_Float16)qg[idx];
                    ksh[dst] = (_Float16)kg[idx];
                    vsh[dst] = (_Float16)vg[idx];
                }
                __syncthreads();
                if (w == 0) {
                    float v6[6] = {0.f, 0.f, 0.f, 0.f, 0.f, 0.f};
                    for (int c = lane; c < TT; c += 64) {
                        #pragma unroll
                        for (int t = 0; t < 6; t++) v6[t] += (float)vsh[c * RSTR + t];
                    }
                    #pragma unroll
                    for (int m = 32; m > 0; m >>= 1) {
                        #pragma unroll
                        for (int t = 0; t < 6; t++) v6[t] += __shfl_xor(v6[t], m, 64);
                    }
                    if (lane < 6) vsh[TT * RSTR + lane] = (_Float16)(v6[lane] * (1.f / TT));
                }
                __syncthreads();

                f32x16 zacc;
                #pragma unroll
                for (int j = 0; j < 16; j++) zacc[j] = 0.f;
                half8 zero8;
                #pragma unroll
                for (int t = 0; t < 8; t++) zero8[t] = (_Float16)0.f;

                half8 bfrag[5], vhalf[5];
                #pragma unroll
                for (int nt = 0; nt < 5; nt++) {
                    int rr = nt * 32 + lo;
                    int rc = rr < 151 ? rr : 151;
                    half8 kf = *(const half8*)&ksh[rc * RSTR];
                    half8 vf = *(const half8*)&vsh[rc * RSTR];
                    bfrag[nt] = hf ? zero8 : kf;
                    vhalf[nt] = hf ? zero8 : vf;
                }

                for (int ap = 0; ap < 2; ap++) {
                    int a = g * 8 + w * 2 + ap;
                    if (a >= TT) break;
                    half8 qav = *(const half8*)&qsh[a * RSTR];
                    half8 afrag[5];
                    #pragma unroll
                    for (int nt = 0; nt < 5; nt++) afrag[nt] = vhalf[nt] * qav;

                    float fsc[5];
                    #pragma unroll
                    for (int nb = 0; nb < 5; nb++) {
                        float rm = -INFINITY;
                        #pragma unroll
                        for (int ma = 0; ma < 4; ma++) {
                            f32x16 acc = __builtin_amdgcn_mfma_f32_32x32x16_f16(afrag[ma], bfrag[nb], zacc, 0, 0, 0);
                            float m = fmaxf(acc[0], acc[1]);
                            #pragma unroll
                            for (int j = 2; j < 16; j += 2) m = fmaxf(fmaxf(m, acc[j]), acc[j + 1]);
                            rm = fmaxf(rm, m);
                        }
                        f32x16 a4 = __builtin_amdgcn_mfma_f32_32x32x16_f16(afrag[4], bfrag[nb], zacc, 0, 0, 0);
                        float m4 = fmaxf(a4[0], a4[1]);
                        #pragma unroll
                        for (int j = 2; j < 10; j += 2) m4 = fmaxf(fmaxf(m4, a4[j]), a4[j + 1]);
                        float ext = (hf == 0) ? fmaxf(a4[10], a4[11]) : -INFINITY;
                        rm = fmaxf(rm, fmaxf(m4, ext));
                        float om = __shfl_xor(a4[10], 32, 64);
                        float mn = hf ? a4[10] : om;
                        rm = fmaxf(rm, __shfl_xor(rm, 32, 64));
                        int bcol = nb * 32 + lo;
                        fsc[nb] = (bcol < TT) ? (mn + rm) : -INFINITY;
                    }
                    float m = fsc[0];
                    #pragma unroll
                    for (int nb = 1; nb < 5; nb++) m = fmaxf(m, fsc[nb]);
                    #pragma unroll
                    for (int msk = 16; msk > 0; msk >>= 1) m = fmaxf(m, __shfl_xor(m, msk, 64));
                    float e[5], es = 0.f;
                    #pragma unroll
                    for (int nb = 0; nb < 5; nb++) { e[nb] = __expf(fsc[nb] - m); es += e[nb]; }
                    #pragma unroll
                    for (int msk = 16; msk > 0; msk >>= 1) es += __shfl_xor(es, msk, 64);
                    float acc6[6] = {0.f, 0.f, 0.f, 0.f, 0.f, 0.f};
                    #pragma unroll
                    for (int nb = 0; nb < 5; nb++) {
                        int bcol = nb * 32 + lo;
                        int bi = (bcol < TT) ? bcol : 0;
                        float wgt = e[nb];
                        half8 qrow = *(const half8*)&qsh[bi * RSTR];
                        #pragma unroll
                        for (int t = 0; t < 6; t++) acc6[t] += wgt * (float)qrow[t];
                    }
                    #pragma unroll
                    for (int msk = 16; msk > 0; msk >>= 1) {
                        #pragma unroll
                        for (int t = 0; t < 6; t++) acc6[t] += __shfl_xor(acc6[t], msk, 64);
                    }
                    if (lane == 0) {
                        float inv = 1.f / es;
                        int bo = i / HH, ho = i % HH;
                        float* dst = P.at + (size_t)s * ROWF + a * (BB * DD) + bo * DD + ho * HD;
                        #pragma unroll
                        for (int t = 0; t < 6; t++) dst[t] = acc6[t] * inv;
                    }
                }
                __syncthreads();
            }
        }
        __threadfence();
        grid.sync();

        // FFN + next-layer q
        {
            float* owS  = sm;
            float* w1T  = sm + 900;
            float* w2S  = sm + 4500;
            float* iwqS = sm + 8130;
            float* arS  = sm + 9030;
            float* xnS  = sm + 9150;
            float* hidS = sm + 9278;
            float* xqS  = sm + 9758;
            int has_next = (l < LL - 1);
            for (int task = bid; task < 600; task += nbk) {
                int s = task / 300;
                int tb = (task % 300) * 4 + w;
                int t = tb / BB, b = tb % BB;
                int po = s * LL + l;
                const float* ow = P.out_w + (size_t)po * 900;
                const float* ob = P.out_b + (size_t)po * 30;
                const float* w1 = P.l1w + (size_t)po * 3600;
                const float* b1 = P.l1b + (size_t)po * 120;
                const float* w2 = P.l2w + (size_t)po * 3600;
                const float* b2 = P.l2b + (size_t)po * 30;
                const float* g2 = P.n2g + (size_t)po * 30;
                const float* bb2 = P.n2b + (size_t)po * 30;
                for (int j = tid; j < 900; j += 256) owS[j] = ow[j];
                for (int j = tid; j < 3600; j += 256) w1T[(j % 30) * 120 + (j / 30)] = w1[j];
                for (int j = tid; j < 3600; j += 256) w2S[(j / 120) * 121 + (j % 120)] = w2[j];
                if (has_next) {
                    const float* iwq = P.in_w + (size_t)(po + 1) * 2700;
                    for (int j = tid; j < 900; j += 256) iwqS[j] = iwq[j];
                }
                float* hrow = P.h + (size_t)s * ROWF + (size_t)tb * 30;
                const float* res = (l == 0) ? (P.pl + (size_t)tb * 30) : hrow;
                const float* arow = P.at + (size_t)s * ROWF + (size_t)tb * 30;
                if (lane < 30) arS[w * 30 + lane] = arow[lane];
                __syncthreads();
                float x1v = 0.f;
                if (lane < 30) {
                    const float* wr = owS + lane * 30;
                    float acc = 0.f;
                    #pragma unroll 6
                    for (int j = 0; j < 30; j++) acc += wr[j] * arS[w * 30 + j];
                    x1v = res[lane] + acc + ob[lane];
                }
                float mean = wsum(x1v) * (1.f / 30.f);
                float dv = (lane < 30) ? (x1v - mean) : 0.f;
                float var = wsum(dv * dv) * (1.f / 30.f);
                float inv = rsqrtf(var + 1e-5f);
                if (lane < 30) xnS[w * 32 + lane] = dv * inv * g2[lane] + bb2[lane];
                for (int o = lane; o < 120; o += 64) {
                    float acc = 0.f;
                    #pragma unroll 6
                    for (int j = 0; j < 30; j++) acc += w1T[j * 120 + o] * xnS[w * 32 + j];
                    hidS[w * 120 + o] = fmaxf(acc + b1[o], 0.f);
                }
                float newh = 0.f;
                if (lane < 30) {
                    const float* wr = w2S + lane * 121;
                    float acc = 0.f;
                    #pragma unroll 8
                    for (int j = 0; j < 120; j++) acc += wr[j] * hidS[w * 120 + j];
                    newh = x1v + acc + b2[lane];
                    hrow[lane] = newh;
                }
                if (has_next) {
                    const float* g1 = P.n1g + (size_t)(po + 1) * 30;
                    const float* bb1 = P.n1b + (size_t)(po + 1) * 30;
                    const float* ibq = P.in_b + (size_t)(po + 1) * 90;
                    float mean2 = wsum(newh) * (1.f / 30.f);
                    float dv2 = (lane < 30) ? (newh - mean2) : 0.f;
                    float var2 = wsum(dv2 * dv2) * (1.f / 30.f);
                    float inv2 = rsqrtf(var2 + 1e-5f);
                    if (lane < 30) xqS[w * 30 + lane] = dv2 * inv2 * g1[lane] + bb1[lane];
                    if (lane < 30) {
                        const float* wr = iwqS + lane * 30;
                        float acc = 0.f;
                        #pragma unroll 6
                        for (int j = 0; j < 30; j++) acc += wr[j] * xqS[w * 30 + j];
                        acc = (acc + ibq[lane]) * 0.40824829046386307f;
                        int i = b * HH + lane / HD, hd = lane % HD;
                        P.q[((size_t)s * NI + i) * (TT * HD) + t * HD + hd] = acc;
                    }
                }
                __syncthreads();
            }
        }
        __threadfence();
        grid.sync();
    }

    // ---- Head (block 0) ----
    if (bid == 0) {
        float* lh  = sm;
        float* hid = sm + 480;
        float* pr  = sm + 960;
        for (int idx = tid; idx < 480; idx += 256) {
            int b = idx / 60, j = idx % 60;
            int s = j / 30, d = j % 30;
            float vv = P.h[(size_t)s * ROWF + 149 * (BB * DD) + b * DD + d];
            lh[idx] = vv;
            P.out[8 + idx] = vv;
        }
        __syncthreads();
        for (int idx = tid; idx < 480; idx += 256) {
            int b = idx / 60, o = idx % 60;
            const float* wr = P.p1w + o * 60;
            float acc = P.p1b[o];
            for (int j = 0; j < 60; j++) acc += wr[j] * lh[b * 60 + j];
            hid[idx] = fmaxf(acc, 0.f);
        }
        __syncthreads();
        for (int idx = tid; idx < 480; idx += 256) {
            int b = idx / 60, d = idx % 60;
            const float* wr = P.p2w + d * 60;
            float acc = P.p2b[d];
            for (int j = 0; j < 60; j++) acc += wr[j] * hid[b * 60 + j];
            pr[idx] = acc + lh[idx];
        }
        __syncthreads();
        if (tid < 8) {
            float acc = P.obb[0];
            for (int j = 0; j < 60; j++) acc += pr[tid * 60 + j] * P.oww[j];
            P.out[tid] = acc;
        }
    }
}

// ===================== FALLBACK kernels (verified round-6 path) =====================
__global__ __launch_bounds__(256) void proj3_kernel(
    const float* __restrict__ x_l, const float* __restrict__ x_a, const float* __restrict__ x_v,
    const float* __restrict__ Wl, const float* __restrict__ Wa, const float* __restrict__ Wv,
    float* __restrict__ pl, float* __restrict__ pa, float* __restrict__ pv) {
    int blk = blockIdx.x;
    int which = blk / 300;
    int w = threadIdx.x >> 6, lane = threadIdx.x & 63;
    int rowu = (blk % 300) * 4 + w;
    int t = rowu / BB, b = rowu % BB;
    const float* x = which == 0 ? x_l : (which == 1 ? x_a : x_v);
    const float* W = which == 0 ? Wl : (which == 1 ? Wa : Wv);
    float* out = which == 0 ? pl : (which == 1 ? pa : pv);
    int Cin = which == 0 ? 300 : (which == 1 ? 74 : 35);
    int cst = Cin | 1;
    __shared__ float WS[30 * 301];
    __shared__ float xr[4][304];
    for (int j = threadIdx.x; j < DD * Cin; j += 256)
        WS[(j / Cin) * cst + (j % Cin)] = W[j];
    const float* xp = x + ((size_t)b * TT + t) * Cin;
    for (int j = lane; j < Cin; j += 64) xr[w][j] = xp[j];
    __syncthreads();
    int d = lane >> 1, jh = lane & 1;
    int h1 = Cin >> 1;
    int j0 = jh ? h1 : 0, j1 = jh ? Cin : h1;
    const float* wr = WS + (size_t)(d < DD ? d : 0) * cst;
    float acc = 0.f;
    for (int j = j0; j < j1; j++) acc += xr[w][j] * wr[j];
    acc += __shfl_xor(acc, 1, 64);
    if (jh == 0 && d < DD) out[t * (BB * DD) + b * DD + d] = acc;
}

__global__ __launch_bounds__(256) void kvpre_kernel(
    const float* __restrict__ pa, const float* __restrict__ pv,
    const float* __restrict__ in_w, const float* __restrict__ in_b,
    const float* __restrict__ n1g, const float* __restrict__ n1b,
    float* __restrict__ k_all, float* __restrict__ v_all) {
    int blk = blockIdx.x;
    int po = blk / 300;
    int s = po / LL;
    int w = threadIdx.x >> 6, lane = threadIdx.x & 63;
    int tb = (blk % 300) * 4 + w;
    int t = tb / BB, b = tb % BB;
    const float* xk = (s == 0) ? pa : pv;
    const float* xv = (s == 0) ? pv : pa;
    const float* iw = in_w + (size_t)po * 2700 + 900;
    const float* ib = in_b + (size_t)po * 90;
    const float* g  = n1g + (size_t)po * 30;
    const float* bb = n1b + (size_t)po * 30;
    __shared__ float iwS[1800];
    __shared__ float xn[4][2][30];
    for (int j = threadIdx.x; j < 1800; j += 256) iwS[j] = iw[j];
    const float* rows[2] = { xk + (size_t)tb * 30, xv + (size_t)tb * 30 };
    for (int r = 0; r < 2; r++) {
        float xval = (lane < 30) ? rows[r][lane] : 0.f;
        float mean = wsum(xval) * (1.f / 30.f);
        float dv = (lane < 30) ? (xval - mean) : 0.f;
        float var = wsum(dv * dv) * (1.f / 30.f);
        float inv = rsqrtf(var + 1e-5f);
        if (lane < 30) xn[w][r][lane] = dv * inv * g[lane] + bb[lane];
    }
    __syncthreads();
    if (lane < 60) {
        int which = lane / 30, dd = lane % 30;
        const float* wr = iwS + lane * 30;
        const float* xv2 = xn[w][which];
        float acc = 0.f;
        #pragma unroll 6
        for (int j = 0; j < 30; j++) acc += wr[j] * xv2[j];
        acc += ib[30 + lane];
        int i = b * HH + dd / HD, hd = dd % HD;
        float* dst = which ? v_all : k_all;
        dst[((size_t)po * NI + i) * (TT * HD) + t * HD + hd] = acc;
    }
}

__global__ __launch_bounds__(256) void lnq0_kernel(
    const float* __restrict__ pl,
    const float* __restrict__ in_w, const float* __restrict__ in_b,
    const float* __restrict__ n1g, const float* __restrict__ n1b,
    float* __restrict__ q) {
    int blk = blockIdx.x;
    int s = blk / 300;
    int w = threadIdx.x >> 6, lane = threadIdx.x & 63;
    int tb = (blk % 300) * 4 + w;
    int t = tb / BB, b = tb % BB;
    int po = s * LL;
    const float* iw = in_w + (size_t)po * 2700;
    const float* ib = in_b + (size_t)po * 90;
    const float* g  = n1g + (size_t)po * 30;
    const float* bb = n1b + (size_t)po * 30;
    __shared__ float iwS[900];
    __shared__ float xn[4][30];
    for (int j = threadIdx.x; j < 900; j += 256) iwS[j] = iw[j];
    const float* row = pl + (size_t)tb * 30;
    float xval = (lane < 30) ? row[lane] : 0.f;
    float mean = wsum(xval) * (1.f / 30.f);
    float dv = (lane < 30) ? (xval - mean) : 0.f;
    float var = wsum(dv * dv) * (1.f / 30.f);
    float inv = rsqrtf(var + 1e-5f);
    if (lane < 30) xn[w][lane] = dv * inv * g[lane] + bb[lane];
    __syncthreads();
    if (lane < 30) {
        const float* wr = iwS + lane * 30;
        float acc = 0.f;
        #pragma unroll 6
        for (int j = 0; j < 30; j++) acc += wr[j] * xn[w][j];
        acc = (acc + ib[lane]) * 0.40824829046386307f;
        int i = b * HH + lane / HD, hd = lane % HD;
        q[((size_t)s * NI + i) * (TT * HD) + t * HD + hd] = acc;
    }
}

__global__ __launch_bounds__(256) void score_kernel(
    const float* __restrict__ q, const float* __restrict__ k_all,
    const float* __restrict__ v_all, int l, float* __restrict__ attn) {
    int blk = blockIdx.x;
    int s = blk / 760;
    int rem = blk % 760;
    int i = rem / 19;
    int g = rem % 19;
    int tid = threadIdx.x;
    int wv = tid >> 6, lane = tid & 63;
    int lo = lane & 31, hf = lane >> 5;
    int po = s * LL + l;
    __shared__ __align__(16) _Float16 qsh[NR * RSTR];
    __shared__ __align__(16) _Float16 ksh[NR * RSTR];
    __shared__ __align__(16) _Float16 vsh[NR * RSTR];
    int* qz = (int*)qsh; int* kz = (int*)ksh; int* vz = (int*)vsh;
    for (int idx = tid; idx < NR * RSTR / 2; idx += 256) { qz[idx] = 0; kz[idx] = 0; vz[idx] = 0; }
    __syncthreads();
    const float* qg = q + (size_t)(s * NI + i) * (TT * HD);
    const float* kg = k_all + (size_t)(po * NI + i) * (TT * HD);
    const float* vg = v_all + (size_t)(po * NI + i) * (TT * HD);
    for (int idx = tid; idx < TT * HD; idx += 256) {
        int dst = (idx / HD) * RSTR + (idx % HD);
        qsh[dst] = (_Float16)qg[idx];
        ksh[dst] = (_Float16)kg[idx];
        vsh[dst] = (_Float16)vg[idx];
    }
    __syncthreads();
    if (wv == 0) {
        float v6[6] = {0.f, 0.f, 0.f, 0.f, 0.f, 0.f};
        for (int c = lane; c < TT; c += 64) {
            #pragma unroll
            for (int t = 0; t < 6; t++) v6[t] += (float)vsh[c * RSTR + t];
        }
        #pragma unroll
        for (int m = 32; m > 0; m >>= 1) {
            #pragma unroll
            for (int t = 0; t < 6; t++) v6[t] += __shfl_xor(v6[t], m, 64);
        }
        if (lane < 6) vsh[TT * RSTR + lane] = (_Float16)(v6[lane] * (1.f / TT));
    }
    __syncthreads();
    f32x16 zacc;
    #pragma unroll
    for (int j = 0; j < 16; j++) zacc[j] = 0.f;
    half8 zero8;
    #pragma unroll
    for (int t = 0; t < 8; t++) zero8[t] = (_Float16)0.f;
    half8 bfrag[5], vhalf[5];
    #pragma unroll
    for (int nt = 0; nt < 5; nt++) {
        int rr = nt * 32 + lo;
        int rc = rr < 151 ? rr : 151;
        half8 kf = *(const half8*)&ksh[rc * RSTR];
        half8 vf = *(const half8*)&vsh[rc * RSTR];
        bfrag[nt] = hf ? zero8 : kf;
        vhalf[nt] = hf ? zero8 : vf;
    }
    for (int ap = 0; ap < 2; ap++) {
        int a = g * 8 + wv * 2 + ap;
        if (a >= TT) break;
        half8 qav = *(const half8*)&qsh[a * RSTR];
        half8 afrag[5];
        #pragma unroll
        for (int nt = 0; nt < 5; nt++) afrag[nt] = vhalf[nt] * qav;
        float fsc[5];
        #pragma unroll
        for (int nb = 0; nb < 5; nb++) {
            float rm = -INFINITY;
            #pragma unroll
            for (int ma = 0; ma < 4; ma++) {
                f32x16 acc = __builtin_amdgcn_mfma_f32_32x32x16_f16(afrag[ma], bfrag[nb], zacc, 0, 0, 0);
                float m = fmaxf(acc[0], acc[1]);
                #pragma unroll
                for (int j = 2; j < 16; j += 2) m = fmaxf(fmaxf(m, acc[j]), acc[j + 1]);
                rm = fmaxf(rm, m);
            }
            f32x16 a4 = __builtin_amdgcn_mfma_f32_32x32x16_f16(afrag[4], bfrag[nb], zacc, 0, 0, 0);
            float m4 = fmaxf(a4[0], a4[1]);
            #pragma unroll
            for (int j = 2; j < 10; j += 2) m4 = fmaxf(fmaxf(m4, a4[j]), a4[j + 1]);
            float ext = (hf == 0) ? fmaxf(a4[10], a4[11]) : -INFINITY;
            rm = fmaxf(rm, fmaxf(m4, ext));
            float om = __shfl_xor(a4[10], 32, 64);
            float mn = hf ? a4[10] : om;
            rm = fmaxf(rm, __shfl_xor(rm, 32, 64));
            int bcol = nb * 32 + lo;
            fsc[nb] = (bcol < TT) ? (mn + rm) : -INFINITY;
        }
        float m = fsc[0];
        #pragma unroll
        for (int nb = 1; nb < 5; nb++) m = fmaxf(m, fsc[nb]);
        #pragma unroll
        for (int msk = 16; msk > 0; msk >>= 1) m = fmaxf(m, __shfl_xor(m, msk, 64));
        float e[5], es = 0.f;
        #pragma unroll
        for (int nb = 0; nb < 5; nb++) { e[nb] = __expf(fsc[nb] - m); es += e[nb]; }
        #pragma unroll
        for (int msk = 16; msk > 0; msk >>= 1) es += __shfl_xor(es, msk, 64);
        float acc6[6] = {0.f, 0.f, 0.f, 0.f, 0.f, 0.f};
        #pragma unroll
        for (int nb = 0; nb < 5; nb++) {
            int bcol = nb * 32 + lo;
            int bi = (bcol < TT) ? bcol : 0;
            float wgt = e[nb];
            half8 qrow = *(const half8*)&qsh[bi * RSTR];
            #pragma unroll
            for (int t = 0; t < 6; t++) acc6[t] += wgt * (float)qrow[t];
        }
        #pragma unroll
        for (int msk = 16; msk > 0; msk >>= 1) {
            #pragma unroll
            for (int t = 0; t < 6; t++) acc6[t] += __shfl_xor(acc6[t], msk, 64);
        }
        if (lane == 0) {
            float inv = 1.f / es;
            int bo = i / HH, ho = i % HH;
            float* dst = attn + (size_t)s * ROWF + a * (BB * DD) + bo * DD + ho * HD;
            #pragma unroll
            for (int t = 0; t < 6; t++) dst[t] = acc6[t] * inv;
        }
    }
}

__global__ __launch_bounds__(256) void ffnlnq_kernel(
    const float* __restrict__ attn, const float* __restrict__ pl,
    const float* __restrict__ out_w, const float* __restrict__ out_b,
    const float* __restrict__ l1w, const float* __restrict__ l1b,
    const float* __restrict__ l2w, const float* __restrict__ l2b,
    const float* __restrict__ n2g, const float* __restrict__ n2b,
    const float* __restrict__ in_w, const float* __restrict__ in_b,
    const float* __restrict__ n1g, const float* __restrict__ n1b,
    int l, int has_next,
    float* __restrict__ h, float* __restrict__ q) {
    int blk = blockIdx.x;
    int s = blk / 300;
    int w = threadIdx.x >> 6, lane = threadIdx.x & 63;
    int tb = (blk % 300) * 4 + w;
    int t = tb / BB, b = tb % BB;
    int po = s * LL + l;
    const float* ow = out_w + (size_t)po * 900;
    const float* ob = out_b + (size_t)po * 30;
    const float* w1 = l1w + (size_t)po * 3600;
    const float* b1 = l1b + (size_t)po * 120;
    const float* w2 = l2w + (size_t)po * 3600;
    const float* b2 = l2b + (size_t)po * 30;
    const float* g2 = n2g + (size_t)po * 30;
    const float* bb2 = n2b + (size_t)po * 30;
    __shared__ float owS[900];
    __shared__ float w1T[30 * 128];
    __shared__ float w2S[30 * 121];
    __shared__ float iwqS[900];
    __shared__ float arS[4][30], xnS[4][32], hidS[4][120], xqS[4][30];
    for (int j = threadIdx.x; j < 900; j += 256) owS[j] = ow[j];
    for (int j = threadIdx.x; j < 3600; j += 256) w1T[(j % 30) * 128 + (j / 30)] = w1[j];
    for (int j = threadIdx.x; j < 3600; j += 256) w2S[(j / 120) * 121 + (j % 120)] = w2[j];
    if (has_next) {
        const float* iwq = in_w + (size_t)(po + 1) * 2700;
        for (int j = threadIdx.x; j < 900; j += 256) iwqS[j] = iwq[j];
    }
    __syncthreads();
    float* hrow = h + (size_t)s * ROWF + (size_t)tb * 30;
    const float* res = (l == 0) ? (pl + (size_t)tb * 30) : hrow;
    const float* arow = attn + (size_t)s * ROWF + (size_t)tb * 30;
    if (lane < 30) arS[w][lane] = arow[lane];
    __syncthreads();
    float x1v = 0.f;
    if (lane < 30) {
        const float* wr = owS + lane * 30;
        float acc = 0.f;
        #pragma unroll 6
        for (int j = 0; j < 30; j++) acc += wr[j] * arS[w][j];
        x1v = res[lane] + acc + ob[lane];
    }
    float mean = wsum(x1v) * (1.f / 30.f);
    float dv = (lane < 30) ? (x1v - mean) : 0.f;
    float var = wsum(dv * dv) * (1.f / 30.f);
    float inv = rsqrtf(var + 1e-5f);
    if (lane < 30) xnS[w][lane] = dv * inv * g2[lane] + bb2[lane];
    for (int o = lane; o < 120; o += 64) {
        float acc = 0.f;
        #pragma unroll 6
        for (int j = 0; j < 30; j++) acc += w1T[j * 128 + o] * xnS[w][j];
        hidS[w][o] = fmaxf(acc + b1[o], 0.f);
    }
    float newh = 0.f;
    if (lane < 30) {
        const float* wr = w2S + lane * 121;
        float acc = 0.f;
        #pragma unroll 8
        for (int j = 0; j < 120; j++) acc += wr[j] * hidS[w][j];
        newh = x1v + acc + b2[lane];
        hrow[lane] = newh;
    }
    if (has_next) {
        const float* g1 = n1g + (size_t)(po + 1) * 30;
        const float* bb1 = n1b + (size_t)(po + 1) * 30;
        const float* ibq = in_b + (size_t)(po + 1) * 90;
        float mean2 = wsum(newh) * (1.f / 30.f);
        float dv2 = (lane < 30) ? (newh - mean2) : 0.f;
        float var2 = wsum(dv2 * dv2) * (1.f / 30.f);
        float inv2 = rsqrtf(var2 + 1e-5f);
        if (lane < 30) xqS[w][lane] = dv2 * inv2 * g1[lane] + bb1[lane];
        if (lane < 30) {
            const float* wr = iwqS + lane * 30;
            float acc = 0.f;
            #pragma unroll 6
            for (int j = 0; j < 30; j++) acc += wr[j] * xqS[w][j];
            acc = (acc + ibq[lane]) * 0.40824829046386307f;
            int i = b * HH + lane / HD, hd = lane % HD;
            q[((size_t)s * NI + i) * (TT * HD) + t * HD + hd] = acc;
        }
    }
}

__global__ __launch_bounds__(256) void head_kernel(
    const float* __restrict__ h,
    const float* __restrict__ p1w, const float* __restrict__ p1b,
    const float* __restrict__ p2w, const float* __restrict__ p2b,
    const float* __restrict__ ow, const float* __restrict__ ob,
    float* __restrict__ out) {
    int tid = threadIdx.x;
    __shared__ float lh[480], hid[480], pr[480];
    for (int idx = tid; idx < 480; idx += 256) {
        int b = idx / 60, j = idx % 60;
        int s = j / 30, d = j % 30;
        float vv = h[(size_t)s * ROWF + 149 * (BB * DD) + b * DD + d];
        lh[idx] = vv;
        out[8 + idx] = vv;
    }
    __syncthreads();
    for (int idx = tid; idx < 480; idx += 256) {
        int b = idx / 60, o = idx % 60;
        const float* wr = p1w + o * 60;
        float acc = p1b[o];
        for (int j = 0; j < 60; j++) acc += wr[j] * lh[b * 60 + j];
        hid[idx] = fmaxf(acc, 0.f);
    }
    __syncthreads();
    for (int idx = tid; idx < 480; idx += 256) {
        int b = idx / 60, d = idx % 60;
        const float* wr = p2w + d * 60;
        float acc = p2b[d];
        for (int j = 0; j < 60; j++) acc += wr[j] * hid[b * 60 + j];
        pr[idx] = acc + lh[idx];
    }
    __syncthreads();
    if (tid < 8) {
        float acc = ob[0];
        for (int j = 0; j < 60; j++) acc += pr[tid * 60 + j] * ow[j];
        out[tid] = acc;
    }
}

extern "C" void kernel_launch(void* const* d_in, const int* in_sizes, int n_in,
                              void* d_out, int out_size, void* d_ws, size_t ws_size,
                              hipStream_t stream) {
    float* ws = (float*)d_ws;
    Params P;
    P.x_l  = (const float*)d_in[0];
    P.x_a  = (const float*)d_in[1];
    P.x_v  = (const float*)d_in[2];
    P.Wl   = (const float*)d_in[3];
    P.Wa   = (const float*)d_in[4];
    P.Wv   = (const float*)d_in[5];
    P.in_w = (const float*)d_in[6];
    P.in_b = (const float*)d_in[7];
    P.out_w = (const float*)d_in[8];
    P.out_b = (const float*)d_in[9];
    P.l1w  = (const float*)d_in[10];
    P.l1b  = (const float*)d_in[11];
    P.l2w  = (const float*)d_in[12];
    P.l2b  = (const float*)d_in[13];
    P.n1g  = (const float*)d_in[14];
    P.n1b  = (const float*)d_in[15];
    P.n2g  = (const float*)d_in[16];
    P.n2b  = (const float*)d_in[17];
    P.p1w  = (const float*)d_in[18];
    P.p1b  = (const float*)d_in[19];
    P.p2w  = (const float*)d_in[20];
    P.p2b  = (const float*)d_in[21];
    P.oww  = (const float*)d_in[22];
    P.obb  = (const float*)d_in[23];
    P.pl    = ws;
    P.pa    = ws + 36000;
    P.pv    = ws + 72000;
    P.h     = ws + 108000;
    P.q     = ws + 180000;
    P.k_all = ws + 252000;
    P.v_all = ws + 468000;
    P.at    = ws + 684000;
    P.out   = (float*)d_out;

    // Host-side capability probe (no stream ops; identical every call).
    int dev = 0;
    hipGetDevice(&dev);
    int coopAttr = 0;
    hipDeviceGetAttribute(&coopAttr, hipDeviceAttributeCooperativeLaunch, dev);
    int cus = 0;
    hipDeviceGetAttribute(&cus, hipDeviceAttributeMultiprocessorCount, dev);
    int maxBpc = 0;
    hipOccupancyMaxActiveBlocksPerMultiprocessor(&maxBpc, mega_kernel, 256, 0);

    bool launched = false;
    if (coopAttr && maxBpc >= 1 && cus >= 1) {
        int blocks = maxBpc * cus;
        if (blocks > 768) blocks = 768;
        void* args[] = { &P };
        hipError_t e = hipLaunchCooperativeKernel((const void*)mega_kernel,
                                                  dim3(blocks), dim3(256), args, 0, stream);
        launched = (e == hipSuccess);
    }
    if (!launched) {
        // verified multi-kernel path
        proj3_kernel<<<900, 256, 0, stream>>>(P.x_l, P.x_a, P.x_v, P.Wl, P.Wa, P.Wv,
                                              P.pl, P.pa, P.pv);
        kvpre_kernel<<<1800, 256, 0, stream>>>(P.pa, P.pv, P.in_w, P.in_b, P.n1g, P.n1b,
                                               P.k_all, P.v_all);
        lnq0_kernel<<<600, 256, 0, stream>>>(P.pl, P.in_w, P.in_b, P.n1g, P.n1b, P.q);
        for (int l = 0; l < LL; l++) {
            score_kernel<<<1520, 256, 0, stream>>>(P.q, P.k_all, P.v_all, l, P.at);
            ffnlnq_kernel<<<600, 256, 0, stream>>>(P.at, P.pl, P.out_w, P.out_b,
                                                   P.l1w, P.l1b, P.l2w, P.l2b,
                                                   P.n2g, P.n2b, P.in_w, P.in_b,
                                                   P.n1g, P.n1b, l, (l < LL - 1) ? 1 : 0,
                                                   P.h, P.q);
        }
        head_kernel<<<1, 256, 0, stream>>>(P.h, P.p1w, P.p1b, P.p2w, P.p2b,
                                           P.oww, P.obb, P.out);
    }
}

// Round 9
// 243.600 us; speedup vs baseline: 3.2742x; 3.2742x over previous
//
#include <hip/hip_runtime.h>
#include <math.h>

// Model dims
#define BB 8
#define TT 150
#define DD 30
#define HH 5
#define HD 6
#define LL 3
#define NI 40            // B*H heads per stream
#define ROWF (TT*BB*DD)  // 36000 floats per [T,B,D] buffer
#define RSTR 8           // padded LDS row stride in halves (16B -> ds_read_b128)
#define NR 152           // padded row count (150 data + vbar + zero)

typedef _Float16 half8 __attribute__((ext_vector_type(8)));
typedef float f32x16 __attribute__((ext_vector_type(16)));

__device__ __forceinline__ float wsum(float v) {
    #pragma unroll
    for (int m = 32; m > 0; m >>= 1) v += __shfl_xor(v, m, 64);
    return v;
}

// All three k=1 conv projections. 300 blocks per input; weights staged in LDS.
__global__ __launch_bounds__(256) void proj3_kernel(
    const float* __restrict__ x_l, const float* __restrict__ x_a, const float* __restrict__ x_v,
    const float* __restrict__ Wl, const float* __restrict__ Wa, const float* __restrict__ Wv,
    float* __restrict__ pl, float* __restrict__ pa, float* __restrict__ pv) {
    int blk = blockIdx.x;                   // [0,900)
    int which = blk / 300;
    int w = threadIdx.x >> 6, lane = threadIdx.x & 63;
    int rowu = (blk % 300) * 4 + w;         // [0,1200)
    int t = rowu / BB, b = rowu % BB;
    const float* x = which == 0 ? x_l : (which == 1 ? x_a : x_v);
    const float* W = which == 0 ? Wl : (which == 1 ? Wa : Wv);
    float* out = which == 0 ? pl : (which == 1 ? pa : pv);
    int Cin = which == 0 ? 300 : (which == 1 ? 74 : 35);
    int cst = Cin | 1;                      // odd LDS row stride -> bank spread
    __shared__ float WS[30 * 301];
    __shared__ float xr[4][304];
    for (int j = threadIdx.x; j < DD * Cin; j += 256)
        WS[(j / Cin) * cst + (j % Cin)] = W[j];
    const float* xp = x + ((size_t)b * TT + t) * Cin;
    for (int j = lane; j < Cin; j += 64) xr[w][j] = xp[j];
    __syncthreads();
    int d = lane >> 1, jh = lane & 1;
    int h1 = Cin >> 1;
    int j0 = jh ? h1 : 0, j1 = jh ? Cin : h1;
    const float* wr = WS + (size_t)(d < DD ? d : 0) * cst;
    float acc = 0.f;
    for (int j = j0; j < j1; j++) acc += xr[w][j] * wr[j];
    acc += __shfl_xor(acc, 1, 64);
    if (jh == 0 && d < DD) out[t * (BB * DD) + b * DD + d] = acc;
}

// Merged: blocks [0,1800) compute k,v for all 6 (s,l); blocks [1800,2400) q for layer 0.
__global__ __launch_bounds__(256) void kvq0_kernel(
    const float* __restrict__ pl, const float* __restrict__ pa, const float* __restrict__ pv,
    const float* __restrict__ in_w, const float* __restrict__ in_b,
    const float* __restrict__ n1g, const float* __restrict__ n1b,
    float* __restrict__ k_all, float* __restrict__ v_all, float* __restrict__ q) {
    int blk = blockIdx.x;                   // [0,2400)
    int w = threadIdx.x >> 6, lane = threadIdx.x & 63;
    __shared__ float iwS[1800];
    __shared__ float xn[4][2][30];
    if (blk < 1800) {
        int po = blk / 300;                 // s*LL+l
        int s = po / LL;
        int tb = (blk % 300) * 4 + w;       // [0,1200)
        int t = tb / BB, b = tb % BB;
        const float* xk = (s == 0) ? pa : pv;
        const float* xv = (s == 0) ? pv : pa;
        const float* iw = in_w + (size_t)po * 2700 + 900;   // k,v rows 30..89
        const float* ib = in_b + (size_t)po * 90;
        const float* g  = n1g + (size_t)po * 30;
        const float* bb = n1b + (size_t)po * 30;
        for (int j = threadIdx.x; j < 1800; j += 256) iwS[j] = iw[j];
        const float* rows[2] = { xk + (size_t)tb * 30, xv + (size_t)tb * 30 };
        for (int r = 0; r < 2; r++) {
            float xval = (lane < 30) ? rows[r][lane] : 0.f;
            float mean = wsum(xval) * (1.f / 30.f);
            float dv = (lane < 30) ? (xval - mean) : 0.f;
            float var = wsum(dv * dv) * (1.f / 30.f);
            float inv = rsqrtf(var + 1e-5f);
            if (lane < 30) xn[w][r][lane] = dv * inv * g[lane] + bb[lane];
        }
        __syncthreads();
        if (lane < 60) {
            int which = lane / 30, dd = lane % 30;
            const float* wr = iwS + lane * 30;
            const float* xv2 = xn[w][which];
            float acc = 0.f;
            #pragma unroll 6
            for (int j = 0; j < 30; j++) acc += wr[j] * xv2[j];
            acc += ib[30 + lane];
            int i = b * HH + dd / HD, hd = dd % HD;
            float* dst = which ? v_all : k_all;
            dst[((size_t)po * NI + i) * (TT * HD) + t * HD + hd] = acc;
        }
    } else {
        int r2 = blk - 1800;                // [0,600)
        int s = r2 / 300;
        int tb = (r2 % 300) * 4 + w;
        int t = tb / BB, b = tb % BB;
        int po = s * LL;                    // layer 0
        const float* iw = in_w + (size_t)po * 2700;   // q rows 0..29
        const float* ib = in_b + (size_t)po * 90;
        const float* g  = n1g + (size_t)po * 30;
        const float* bb = n1b + (size_t)po * 30;
        for (int j = threadIdx.x; j < 900; j += 256) iwS[j] = iw[j];
        const float* row = pl + (size_t)tb * 30;
        float xval = (lane < 30) ? row[lane] : 0.f;
        float mean = wsum(xval) * (1.f / 30.f);
        float dv = (lane < 30) ? (xval - mean) : 0.f;
        float var = wsum(dv * dv) * (1.f / 30.f);
        float inv = rsqrtf(var + 1e-5f);
        if (lane < 30) xn[w][0][lane] = dv * inv * g[lane] + bb[lane];
        __syncthreads();
        if (lane < 30) {
            const float* wr = iwS + lane * 30;
            float acc = 0.f;
            #pragma unroll 6
            for (int j = 0; j < 30; j++) acc += wr[j] * xn[w][0][j];
            acc = (acc + ib[lane]) * 0.40824829046386307f;   // HD^-0.5
            int i = b * HH + lane / HD, hd = lane % HD;
            q[((size_t)s * NI + i) * (TT * HD) + t * HD + hd] = acc;
        }
    }
}

// Score kernel: block = (s, head i, g); stages ONE head f16 in LDS (7.3 KB),
// 4 waves x 2 a's. Fused scores via mfma_f32_32x32x16_f16; vbar row c=150
// provides the mean for free; softmax; attn = sum_b p*q -> global.
// C/D layout: col = lane&31, row = (reg&3) + 8*(reg>>2) + 4*(lane>>5).
__global__ __launch_bounds__(256) void score_kernel(
    const float* __restrict__ q, const float* __restrict__ k_all,
    const float* __restrict__ v_all, int l, float* __restrict__ attn) {
    int blk = blockIdx.x;                   // [0, 1520)
    int s = blk / 760;
    int rem = blk % 760;
    int i = rem / 19;
    int g = rem % 19;
    int tid = threadIdx.x;
    int wv = tid >> 6, lane = tid & 63;
    int lo = lane & 31, hf = lane >> 5;
    int po = s * LL + l;

    __shared__ __align__(16) _Float16 qsh[NR * RSTR];
    __shared__ __align__(16) _Float16 ksh[NR * RSTR];
    __shared__ __align__(16) _Float16 vsh[NR * RSTR];

    const float* qg = q + (size_t)(s * NI + i) * (TT * HD);
    const float* kg = k_all + (size_t)(po * NI + i) * (TT * HD);
    const float* vg = v_all + (size_t)(po * NI + i) * (TT * HD);
    // one padded half8 row per thread (rows 150/151 zeroed; vbar fills 150 later)
    half8 z8;
    #pragma unroll
    for (int t = 0; t < 8; t++) z8[t] = (_Float16)0.f;
    for (int r = tid; r < NR; r += 256) {
        half8 qa = z8, ka = z8, va = z8;
        if (r < TT) {
            #pragma unroll
            for (int t = 0; t < 6; t++) {
                qa[t] = (_Float16)qg[r * 6 + t];
                ka[t] = (_Float16)kg[r * 6 + t];
                va[t] = (_Float16)vg[r * 6 + t];
            }
        }
        *(half8*)&qsh[r * RSTR] = qa;
        *(half8*)&ksh[r * RSTR] = ka;
        *(half8*)&vsh[r * RSTR] = va;
    }
    __syncthreads();
    if (wv == 0) {   // vbar row (pre-scaled by 1/150) into vsh row 150
        float v6[6] = {0.f, 0.f, 0.f, 0.f, 0.f, 0.f};
        for (int c = lane; c < TT; c += 64) {
            #pragma unroll
            for (int t = 0; t < 6; t++) v6[t] += (float)vsh[c * RSTR + t];
        }
        #pragma unroll
        for (int m = 32; m > 0; m >>= 1) {
            #pragma unroll
            for (int t = 0; t < 6; t++) v6[t] += __shfl_xor(v6[t], m, 64);
        }
        if (lane < 6) vsh[TT * RSTR + lane] = (_Float16)(v6[lane] * (1.f / TT));
    }
    __syncthreads();

    f32x16 zacc;
    #pragma unroll
    for (int j = 0; j < 16; j++) zacc[j] = 0.f;

    half8 bfrag[5], vhalf[5];
    #pragma unroll
    for (int nt = 0; nt < 5; nt++) {
        int rr = nt * 32 + lo;
        int rc = rr < 151 ? rr : 151;          // 150 = vbar, 151 = zeros
        half8 kf = *(const half8*)&ksh[rc * RSTR];
        half8 vf = *(const half8*)&vsh[rc * RSTR];
        bfrag[nt] = hf ? z8 : kf;
        vhalf[nt] = hf ? z8 : vf;
    }

    for (int ap = 0; ap < 2; ap++) {
        int a = g * 8 + wv * 2 + ap;
        if (a >= TT) break;
        half8 qav = *(const half8*)&qsh[a * RSTR];
        half8 afrag[5];
        #pragma unroll
        for (int nt = 0; nt < 5; nt++) afrag[nt] = vhalf[nt] * qav;  // v_pk_mul_f16

        float fsc[5];
        #pragma unroll
        for (int nb = 0; nb < 5; nb++) {
            float rm = -INFINITY;
            #pragma unroll
            for (int ma = 0; ma < 4; ma++) {
                f32x16 acc = __builtin_amdgcn_mfma_f32_32x32x16_f16(afrag[ma], bfrag[nb], zacc, 0, 0, 0);
                float m = fmaxf(acc[0], acc[1]);
                #pragma unroll
                for (int j = 2; j < 16; j += 2) m = fmaxf(fmaxf(m, acc[j]), acc[j + 1]);
                rm = fmaxf(rm, m);
            }
            f32x16 a4 = __builtin_amdgcn_mfma_f32_32x32x16_f16(afrag[4], bfrag[nb], zacc, 0, 0, 0);
            // live rows: hf==0 -> regs 0..11 (c<=147); hf==1 -> regs 0..9 (c<=149)
            float m4 = fmaxf(a4[0], a4[1]);
            #pragma unroll
            for (int j = 2; j < 10; j += 2) m4 = fmaxf(fmaxf(m4, a4[j]), a4[j + 1]);
            float ext = (hf == 0) ? fmaxf(a4[10], a4[11]) : -INFINITY;
            rm = fmaxf(rm, fmaxf(m4, ext));
            // mean sits at reg10 of hf==1 lanes (row c==150 = vbar row)
            float om = __shfl_xor(a4[10], 32, 64);
            float mn = hf ? a4[10] : om;
            rm = fmaxf(rm, __shfl_xor(rm, 32, 64));
            int bcol = nb * 32 + lo;
            fsc[nb] = (bcol < TT) ? (mn + rm) : -INFINITY;
        }
        float m = fsc[0];
        #pragma unroll
        for (int nb = 1; nb < 5; nb++) m = fmaxf(m, fsc[nb]);
        #pragma unroll
        for (int msk = 16; msk > 0; msk >>= 1) m = fmaxf(m, __shfl_xor(m, msk, 64));
        float e[5], es = 0.f;
        #pragma unroll
        for (int nb = 0; nb < 5; nb++) { e[nb] = __expf(fsc[nb] - m); es += e[nb]; }
        #pragma unroll
        for (int msk = 16; msk > 0; msk >>= 1) es += __shfl_xor(es, msk, 64);
        float acc6[6] = {0.f, 0.f, 0.f, 0.f, 0.f, 0.f};
        #pragma unroll
        for (int nb = 0; nb < 5; nb++) {
            int bcol = nb * 32 + lo;
            int bi = (bcol < TT) ? bcol : 0;
            float wgt = e[nb];
            half8 qrow = *(const half8*)&qsh[bi * RSTR];
            #pragma unroll
            for (int t = 0; t < 6; t++) acc6[t] += wgt * (float)qrow[t];
        }
        #pragma unroll
        for (int msk = 16; msk > 0; msk >>= 1) {
            #pragma unroll
            for (int t = 0; t < 6; t++) acc6[t] += __shfl_xor(acc6[t], msk, 64);
        }
        if (lane == 0) {
            float inv = 1.f / es;
            int bo = i / HH, ho = i % HH;
            float* dst = attn + (size_t)s * ROWF + a * (BB * DD) + bo * DD + ho * HD;
            #pragma unroll
            for (int t = 0; t < 6; t++) dst[t] = acc6[t] * inv;
        }
    }
}

// FFN for layer l + q-projection for layer l+1 (exact per-row fusion).
__global__ __launch_bounds__(256) void ffnlnq_kernel(
    const float* __restrict__ attn, const float* __restrict__ pl,
    const float* __restrict__ out_w, const float* __restrict__ out_b,
    const float* __restrict__ l1w, const float* __restrict__ l1b,
    const float* __restrict__ l2w, const float* __restrict__ l2b,
    const float* __restrict__ n2g, const float* __restrict__ n2b,
    const float* __restrict__ in_w, const float* __restrict__ in_b,
    const float* __restrict__ n1g, const float* __restrict__ n1b,
    int l, int has_next,
    float* __restrict__ h, float* __restrict__ q) {
    int blk = blockIdx.x;                   // [0,600)
    int s = blk / 300;
    int w = threadIdx.x >> 6, lane = threadIdx.x & 63;
    int tb = (blk % 300) * 4 + w;           // [0,1200)
    int t = tb / BB, b = tb % BB;
    int po = s * LL + l;
    const float* ow = out_w + (size_t)po * 900;
    const float* ob = out_b + (size_t)po * 30;
    const float* w1 = l1w + (size_t)po * 3600;
    const float* b1 = l1b + (size_t)po * 120;
    const float* w2 = l2w + (size_t)po * 3600;
    const float* b2 = l2b + (size_t)po * 30;
    const float* g2 = n2g + (size_t)po * 30;
    const float* bb2 = n2b + (size_t)po * 30;
    __shared__ float owS[900];
    __shared__ float w1T[30 * 128];
    __shared__ float w2S[30 * 121];
    __shared__ float iwqS[900];
    __shared__ float arS[4][30], xnS[4][32], hidS[4][120], xqS[4][30];
    for (int j = threadIdx.x; j < 900; j += 256) owS[j] = ow[j];
    for (int j = threadIdx.x; j < 3600; j += 256) w1T[(j % 30) * 128 + (j / 30)] = w1[j];
    for (int j = threadIdx.x; j < 3600; j += 256) w2S[(j / 120) * 121 + (j % 120)] = w2[j];
    if (has_next) {
        const float* iwq = in_w + (size_t)(po + 1) * 2700;
        for (int j = threadIdx.x; j < 900; j += 256) iwqS[j] = iwq[j];
    }
    __syncthreads();
    float* hrow = h + (size_t)s * ROWF + (size_t)tb * 30;
    const float* res = (l == 0) ? (pl + (size_t)tb * 30) : hrow;
    const float* arow = attn + (size_t)s * ROWF + (size_t)tb * 30;
    if (lane < 30) arS[w][lane] = arow[lane];
    float x1v = 0.f;
    if (lane < 30) {
        const float* wr = owS + lane * 30;
        float acc = 0.f;
        #pragma unroll 6
        for (int j = 0; j < 30; j++) acc += wr[j] * arS[w][j];
        x1v = res[lane] + acc + ob[lane];
    }
    float mean = wsum(x1v) * (1.f / 30.f);
    float dv = (lane < 30) ? (x1v - mean) : 0.f;
    float var = wsum(dv * dv) * (1.f / 30.f);
    float inv = rsqrtf(var + 1e-5f);
    if (lane < 30) xnS[w][lane] = dv * inv * g2[lane] + bb2[lane];
    for (int o = lane; o < 120; o += 64) {
        float acc = 0.f;
        #pragma unroll 6
        for (int j = 0; j < 30; j++) acc += w1T[j * 128 + o] * xnS[w][j];
        hidS[w][o] = fmaxf(acc + b1[o], 0.f);
    }
    float newh = 0.f;
    if (lane < 30) {
        const float* wr = w2S + lane * 121;
        float acc = 0.f;
        #pragma unroll 8
        for (int j = 0; j < 120; j++) acc += wr[j] * hidS[w][j];
        newh = x1v + acc + b2[lane];
        hrow[lane] = newh;
    }
    if (has_next) {
        const float* g1 = n1g + (size_t)(po + 1) * 30;
        const float* bb1 = n1b + (size_t)(po + 1) * 30;
        const float* ibq = in_b + (size_t)(po + 1) * 90;
        float mean2 = wsum(newh) * (1.f / 30.f);
        float dv2 = (lane < 30) ? (newh - mean2) : 0.f;
        float var2 = wsum(dv2 * dv2) * (1.f / 30.f);
        float inv2 = rsqrtf(var2 + 1e-5f);
        if (lane < 30) xqS[w][lane] = dv2 * inv2 * g1[lane] + bb1[lane];
        if (lane < 30) {
            const float* wr = iwqS + lane * 30;
            float acc = 0.f;
            #pragma unroll 6
            for (int j = 0; j < 30; j++) acc += wr[j] * xqS[w][j];
            acc = (acc + ibq[lane]) * 0.40824829046386307f;
            int i = b * HH + lane / HD, hd = lane % HD;
            q[((size_t)s * NI + i) * (TT * HD) + t * HD + hd] = acc;
        }
    }
}

// Final head: last_hs, proj MLP + residual, scalar out. Writes all 488 outputs.
__global__ __launch_bounds__(256) void head_kernel(
    const float* __restrict__ h,
    const float* __restrict__ p1w, const float* __restrict__ p1b,
    const float* __restrict__ p2w, const float* __restrict__ p2b,
    const float* __restrict__ ow, const float* __restrict__ ob,
    float* __restrict__ out) {
    int tid = threadIdx.x;
    __shared__ float lh[480], hid[480], pr[480];
    for (int idx = tid; idx < 480; idx += 256) {
        int b = idx / 60, j = idx % 60;
        int s = j / 30, d = j % 30;
        float vv = h[(size_t)s * ROWF + 149 * (BB * DD) + b * DD + d];
        lh[idx] = vv;
        out[8 + idx] = vv;   // last_hs
    }
    __syncthreads();
    for (int idx = tid; idx < 480; idx += 256) {
        int b = idx / 60, o = idx % 60;
        const float* wr = p1w + o * 60;
        float acc = p1b[o];
        for (int j = 0; j < 60; j++) acc += wr[j] * lh[b * 60 + j];
        hid[idx] = fmaxf(acc, 0.f);
    }
    __syncthreads();
    for (int idx = tid; idx < 480; idx += 256) {
        int b = idx / 60, d = idx % 60;
        const float* wr = p2w + d * 60;
        float acc = p2b[d];
        for (int j = 0; j < 60; j++) acc += wr[j] * hid[b * 60 + j];
        pr[idx] = acc + lh[idx];
    }
    __syncthreads();
    if (tid < 8) {
        float acc = ob[0];
        for (int j = 0; j < 60; j++) acc += pr[tid * 60 + j] * ow[j];
        out[tid] = acc;      // out
    }
}

extern "C" void kernel_launch(void* const* d_in, const int* in_sizes, int n_in,
                              void* d_out, int out_size, void* d_ws, size_t ws_size,
                              hipStream_t stream) {
    const float* x_l   = (const float*)d_in[0];
    const float* x_a   = (const float*)d_in[1];
    const float* x_v   = (const float*)d_in[2];
    const float* Wl    = (const float*)d_in[3];
    const float* Wa    = (const float*)d_in[4];
    const float* Wv    = (const float*)d_in[5];
    const float* in_w  = (const float*)d_in[6];
    const float* in_b  = (const float*)d_in[7];
    const float* out_w = (const float*)d_in[8];
    const float* out_b = (const float*)d_in[9];
    const float* l1w   = (const float*)d_in[10];
    const float* l1b   = (const float*)d_in[11];
    const float* l2w   = (const float*)d_in[12];
    const float* l2b   = (const float*)d_in[13];
    const float* n1g   = (const float*)d_in[14];
    const float* n1b   = (const float*)d_in[15];
    const float* n2g   = (const float*)d_in[16];
    const float* n2b   = (const float*)d_in[17];
    const float* p1w   = (const float*)d_in[18];
    const float* p1b   = (const float*)d_in[19];
    const float* p2w   = (const float*)d_in[20];
    const float* p2b   = (const float*)d_in[21];
    const float* oww   = (const float*)d_in[22];
    const float* obb   = (const float*)d_in[23];

    float* ws = (float*)d_ws;
    float* pl    = ws;             // 36000
    float* pa    = ws + 36000;     // 36000
    float* pv    = ws + 72000;     // 36000
    float* h     = ws + 108000;    // 72000  [2][T][B][D]
    float* q     = ws + 180000;    // 72000  [2][NI][TT][HD]
    float* k_all = ws + 252000;    // 216000 [6][NI][TT][HD]
    float* v_all = ws + 468000;    // 216000
    float* at    = ws + 684000;    // 72000

    proj3_kernel<<<900, 256, 0, stream>>>(x_l, x_a, x_v, Wl, Wa, Wv, pl, pa, pv);
    kvq0_kernel<<<2400, 256, 0, stream>>>(pl, pa, pv, in_w, in_b, n1g, n1b,
                                          k_all, v_all, q);
    for (int l = 0; l < LL; l++) {
        score_kernel<<<1520, 256, 0, stream>>>(q, k_all, v_all, l, at);
        ffnlnq_kernel<<<600, 256, 0, stream>>>(at, pl, out_w, out_b, l1w, l1b, l2w, l2b,
                                               n2g, n2b, in_w, in_b, n1g, n1b,
                                               l, (l < LL - 1) ? 1 : 0, h, q);
    }
    head_kernel<<<1, 256, 0, stream>>>(h, p1w, p1b, p2w, p2b, oww, obb, (float*)d_out);
}